// Round 17
// baseline (438.764 us; speedup 1.0000x reference)
//
#include <hip/hip_runtime.h>
#include <hip/hip_bf16.h>

// Clockwork RNN. Round 17: chunked scan (L=8) for mi=0,1; R13 elsewhere.
//   k_pow: P[mi][w] = A_mi^{w+1}, w=0..7 (f32, 128x128 each), 2 blocks.
//   k_s:   s_{c,i} = sum_{p<i} A^{i-p} u_{8c+p} + u_{8c+i}  -> xwb dead cols.
//   k_comb: v6 k_phase with A^8, u-ring = s at t=(8K+7)<<mi, storer slot 8K+7.
//   k_exp: h_{8c+i} = A^{i+1} bnd_{c-1} + s_{c,i}, i=0..6 -> hmod.
// mi=7..2: R13 k_u + k_phase verbatim. k_xw / k_out unchanged.

#define TT 256
#define BB 128
#define INW 512
#define HH 128
#define MHW 1024

typedef __bf16 bf16x8 __attribute__((ext_vector_type(8)));
typedef __bf16 bf16x4 __attribute__((ext_vector_type(4)));
typedef float f32x4 __attribute__((ext_vector_type(4)));

__constant__ unsigned int c_hmod_off[8] = {
    0u, 4194304u, 6291456u, 7340032u, 7864320u, 8126464u, 8257536u, 8323072u};

__device__ __forceinline__ unsigned short f2bf(float f) {
    union { float f; unsigned int u; } v{f};
    unsigned int r = v.u + 0x7FFFu + ((v.u >> 16) & 1u);  // RNE
    return (unsigned short)(r >> 16);
}
__device__ __forceinline__ unsigned int pack2(float lo, float hi) {
    return (unsigned int)f2bf(lo) | ((unsigned int)f2bf(hi) << 16);
}
__device__ __forceinline__ float bf2f(unsigned short u) {
    union { unsigned int i; float f; } v;
    v.i = ((unsigned int)u) << 16;
    return v.f;
}

__device__ __forceinline__ void gld_lds16(const void* g, char* l) {
    __builtin_amdgcn_global_load_lds(
        (const __attribute__((address_space(1))) void*)g,
        (__attribute__((address_space(3))) void*)l, 16, 0, 0);
}

// Batch-load a [128][64] f32 tile: 8 independent float4 per thread.
__device__ __forceinline__ void stage_load(float4 (&v)[8],
                                           const float* __restrict__ src,
                                           int stride, int tid) {
    int k4 = (tid & 15) * 4;
    int r0 = tid >> 4;
#pragma unroll
    for (int p = 0; p < 8; ++p)
        v[p] = *reinterpret_cast<const float4*>(src + (size_t)(p * 16 + r0) * stride + k4);
}
// Convert + write staged tile into LDS (bf16, XOR-swizzled rows).
__device__ __forceinline__ void stage_write(char* dst, const float4 (&v)[8], int tid) {
    int k8 = (tid & 15) * 8;
    int r0 = tid >> 4;
#pragma unroll
    for (int p = 0; p < 8; ++p) {
        int row = p * 16 + r0;
        ushort4 b;
        b.x = f2bf(v[p].x); b.y = f2bf(v[p].y);
        b.z = f2bf(v[p].z); b.w = f2bf(v[p].w);
        int off = (row * 128 + k8) ^ ((row & 7) << 4);
        *reinterpret_cast<ushort4*>(dst + off) = b;
    }
}

// Read one 16x32 bf16 fragment from a swizzled bf16 tile ([rows][64] bf16).
__device__ __forceinline__ bf16x8 frag_ld(const char* tile, int row, int ks, int lane) {
    int off = (row * 128 + ks * 64 + (lane >> 4) * 16) ^ ((row & 7) << 4);
    return *reinterpret_cast<const bf16x8*>(tile + off);
}
// Read one fragment from a swizzled f32 tile ([rows][64] f32), cvt to bf16x8.
__device__ __forceinline__ bf16x8 frag_ld_f32(const char* tile, int row, int ks, int g) {
    int off = ((row << 8) + ks * 128 + g * 32) ^ ((row & 7) << 4);
    f32x4 a = *reinterpret_cast<const f32x4*>(tile + off);
    f32x4 b = *reinterpret_cast<const f32x4*>(tile + (off ^ 16));
    bf16x8 u;
    u[0] = (__bf16)a[0]; u[1] = (__bf16)a[1]; u[2] = (__bf16)a[2]; u[3] = (__bf16)a[3];
    u[4] = (__bf16)b[0]; u[5] = (__bf16)b[1]; u[6] = (__bf16)b[2]; u[7] = (__bf16)b[3];
    return u;
}

// 128x128 MFMA block over one [128][64] tile pair (both bf16).
__device__ __forceinline__ void mfma_tile(const char* sA, const char* sB,
                                          f32x4 (&acc)[4][4], int lane,
                                          int wr, int wc) {
#pragma unroll
    for (int ks = 0; ks < 2; ++ks) {
        bf16x8 fa[4], fb[4];
#pragma unroll
        for (int i = 0; i < 4; ++i) {
            fa[i] = frag_ld(sA, wr + i * 16 + (lane & 15), ks, lane);
            fb[i] = frag_ld(sB, wc + i * 16 + (lane & 15), ks, lane);
        }
#pragma unroll
        for (int i = 0; i < 4; ++i)
#pragma unroll
            for (int j = 0; j < 4; ++j)
                acc[i][j] = __builtin_amdgcn_mfma_f32_16x16x32_bf16(
                    fa[i], fb[j], acc[i][j], 0, 0, 0);
    }
}

// ---------------------------------------------------------------------------
// K_xw (unchanged R13)
// ---------------------------------------------------------------------------
__global__ __launch_bounds__(256) void k_xw(const float* __restrict__ x,
                                            const float* __restrict__ Wxh,
                                            const float* __restrict__ bh,
                                            float* __restrict__ xwb) {
    __shared__ char ldsW[2][32768];
    __shared__ char ldsX[2][16384];
    int id = blockIdx.x >> 1, half = blockIdx.x & 1;
    int rt = 0, rem = id;
    while (rem >= (256 >> rt)) { rem -= 256 >> rt; ++rt; }
    int t = rem << rt;

    int tid = threadIdx.x, lane = tid & 63, wid = tid >> 6;
    int l15 = lane & 15, g = lane >> 4;
    int wr = (wid >> 1) * 64, wc = (wid & 1) * 32;

    const float* gW[8];
    const float* gX[4];
    {
        int kb = (lane & 15) * 16;
#pragma unroll
        for (int i = 0; i < 8; ++i) {
            int row = i * 16 + wid * 4 + (lane >> 4);
            int kf = (kb ^ ((row & 7) << 4)) >> 2;
            gW[i] = Wxh + (size_t)(rt * 128 + row) * INW + kf;
        }
#pragma unroll
        for (int i = 0; i < 4; ++i) {
            int row = i * 16 + wid * 4 + (lane >> 4);
            int kf = (kb ^ ((row & 7) << 4)) >> 2;
            gX[i] = x + ((size_t)t * BB + half * 64 + row) * INW + kf;
        }
    }
#pragma unroll
    for (int i = 0; i < 8; ++i)
        gld_lds16(gW[i], &ldsW[0][0] + i * 4096 + wid * 1024);
#pragma unroll
    for (int i = 0; i < 4; ++i)
        gld_lds16(gX[i], &ldsX[0][0] + i * 4096 + wid * 1024);

    f32x4 acc[4][2] = {};
    for (int c = 0; c < 8; ++c) {
        int cur = c & 1;
        __syncthreads();
        if (c < 7) {
#pragma unroll
            for (int i = 0; i < 8; ++i)
                gld_lds16(gW[i] + (c + 1) * 64,
                          &ldsW[cur ^ 1][0] + i * 4096 + wid * 1024);
#pragma unroll
            for (int i = 0; i < 4; ++i)
                gld_lds16(gX[i] + (c + 1) * 64,
                          &ldsX[cur ^ 1][0] + i * 4096 + wid * 1024);
        }
#pragma unroll
        for (int ks = 0; ks < 2; ++ks) {
            bf16x8 fa[4], fb[2];
#pragma unroll
            for (int i = 0; i < 4; ++i)
                fa[i] = frag_ld_f32(&ldsW[cur][0], wr + i * 16 + l15, ks, g);
#pragma unroll
            for (int j = 0; j < 2; ++j)
                fb[j] = frag_ld_f32(&ldsX[cur][0], wc + j * 16 + l15, ks, g);
#pragma unroll
            for (int i = 0; i < 4; ++i)
#pragma unroll
                for (int j = 0; j < 2; ++j)
                    acc[i][j] = __builtin_amdgcn_mfma_f32_16x16x32_bf16(
                        fa[i], fb[j], acc[i][j], 0, 0, 0);
        }
    }
#pragma unroll
    for (int i = 0; i < 4; ++i) {
        int rbase = rt * 128 + wr + i * 16 + g * 4;
        float4 bias = *reinterpret_cast<const float4*>(&bh[rbase]);
#pragma unroll
        for (int j = 0; j < 2; ++j) {
            int b = half * 64 + wc + j * 16 + l15;
            float4 v = make_float4(acc[i][j][0] + bias.x, acc[i][j][1] + bias.y,
                                   acc[i][j][2] + bias.z, acc[i][j][3] + bias.w);
            *reinterpret_cast<float4*>(
                &xwb[(size_t)(t * BB + b) * MHW + rbase]) = v;
        }
    }
}

// ---------------------------------------------------------------------------
// K_pow: P[mi*8 + w] = A_mi^{w+1}, f32 [128][128], mi = blockIdx.x in {0,1}.
// Running power X kept as bf16 LDS tiles; B = A^T bf16 (staged once).
// ---------------------------------------------------------------------------
__global__ __launch_bounds__(256) void k_pow(const float* __restrict__ Whh,
                                             float* __restrict__ P) {
    int mi = blockIdx.x;
    __shared__ char X[2][16384];   // current power, bf16 tiles (k-chunk major)
    __shared__ char Bt[2][16384];  // A^T bf16 tiles
    int tid = threadIdx.x, lane = tid & 63, wid = tid >> 6;
    int l15 = lane & 15, g = lane >> 4;
    int wr = (wid >> 1) * 64, wc = (wid & 1) * 64;
    const float* Ab = Whh + (size_t)(mi * HH) * MHW + mi * HH;
    float* Pm = P + (size_t)mi * 8 * 16384;

    // stage X = A (row-major) and Bt = A^T; copy P[0] = A (f32)
#pragma unroll
    for (int ck = 0; ck < 2; ++ck) {
        float4 vA[8];
        stage_load(vA, Ab + ck * 64, MHW, tid);
        stage_write(&X[ck][0], vA, tid);
        int k4 = (tid & 15) * 4;
        int r0 = tid >> 4;
#pragma unroll
        for (int p = 0; p < 8; ++p) {
            int row = p * 16 + r0;
            ushort4 b;
            b.x = f2bf(Ab[(size_t)(ck * 64 + k4 + 0) * MHW + row]);
            b.y = f2bf(Ab[(size_t)(ck * 64 + k4 + 1) * MHW + row]);
            b.z = f2bf(Ab[(size_t)(ck * 64 + k4 + 2) * MHW + row]);
            b.w = f2bf(Ab[(size_t)(ck * 64 + k4 + 3) * MHW + row]);
            int off = (row * 128 + k4 * 2) ^ ((row & 7) << 4);
            *reinterpret_cast<ushort4*>(&Bt[ck][0] + off) = b;
        }
    }
    for (int idx = tid * 4; idx < 16384; idx += 1024) {
        int r = idx >> 7, cq = idx & 127;
        *reinterpret_cast<float4*>(&Pm[idx]) =
            *reinterpret_cast<const float4*>(&Ab[(size_t)r * MHW + cq]);
    }
    __syncthreads();

    for (int q = 1; q < 8; ++q) {
        f32x4 acc[4][4] = {};
        mfma_tile(&X[0][0], &Bt[0][0], acc, lane, wr, wc);
        mfma_tile(&X[1][0], &Bt[1][0], acc, lane, wr, wc);
        __syncthreads();  // all reads of X done before overwrite
        float* Pq = Pm + (size_t)q * 16384;
#pragma unroll
        for (int i = 0; i < 4; ++i) {
            int r0 = wr + i * 16 + g * 4;
#pragma unroll
            for (int jq = 0; jq < 4; ++jq) {
                int c = wc + jq * 16 + l15;
#pragma unroll
                for (int rr = 0; rr < 4; ++rr) {
                    float v = acc[i][jq][rr];
                    Pq[(size_t)(r0 + rr) * 128 + c] = v;
                    int ck = c >> 6;
                    int off = (((r0 + rr) * 128) + (c & 63) * 2) ^
                              (((r0 + rr) & 7) << 4);
                    *reinterpret_cast<__bf16*>(&X[ck][0] + off) = (__bf16)v;
                }
            }
        }
        __syncthreads();
    }
}

// ---------------------------------------------------------------------------
// K_u (unchanged R13)
// ---------------------------------------------------------------------------
__global__ __launch_bounds__(256) void k_u(const float* __restrict__ Whh,
                                           const float* __restrict__ hprev,
                                           const unsigned short* __restrict__ hmod,
                                           float* __restrict__ xwb, int mi) {
    __shared__ char lds[131072];
    char* ldsA0 = lds;
    char* ldsA1 = lds + 32768;
    char* ldsH0 = lds + 65536;
    char* ldsH1 = lds + 98304;
    int k = blockIdx.x;
    int t = k << mi;
    int tid = threadIdx.x, lane = tid & 63, wid = tid >> 6;
    int l15 = lane & 15, g = lane >> 4;
    int wr = (wid >> 1) * 64, wc = (wid & 1) * 64;
    int ntile = 2 * (7 - mi);

    const float* gA[8];
    {
        int kb = l15 * 16;
#pragma unroll
        for (int i = 0; i < 8; ++i) {
            int row = i * 16 + wid * 4 + g;
            int kf = (kb ^ ((row & 7) << 4)) >> 2;
            gA[i] = Whh + (size_t)(mi * HH + row) * MHW + kf;
        }
    }
    f32x4 acc[4][4] = {};

    if (k == 0) {
        const float* gH[8];
        {
            int kb = l15 * 16;
#pragma unroll
            for (int i = 0; i < 8; ++i) {
                int row = i * 16 + wid * 4 + g;
                int kf = (kb ^ ((row & 7) << 4)) >> 2;
                gH[i] = hprev + (size_t)row * MHW + kf;
            }
        }
        auto stage = [&](int tt, char* dA, char* dH) {
            int j = mi + 1 + (tt >> 1), c0 = (tt & 1) * 64;
            int off = j * HH + c0;
#pragma unroll
            for (int i = 0; i < 8; ++i)
                gld_lds16(gA[i] + off, dA + i * 4096 + wid * 1024);
#pragma unroll
            for (int i = 0; i < 8; ++i)
                gld_lds16(gH[i] + off, dH + i * 4096 + wid * 1024);
        };
        stage(0, ldsA0, ldsH0);
        for (int tt = 0; tt < ntile; ++tt) {
            int cur = tt & 1;
            __syncthreads();
            if (tt + 1 < ntile)
                stage(tt + 1, cur ? ldsA0 : ldsA1, cur ? ldsH0 : ldsH1);
            const char* sA = cur ? ldsA1 : ldsA0;
            const char* sH = cur ? ldsH1 : ldsH0;
#pragma unroll
            for (int ks = 0; ks < 2; ++ks) {
                bf16x8 fa[4], fb[4];
#pragma unroll
                for (int i = 0; i < 4; ++i) {
                    fa[i] = frag_ld_f32(sA, wr + i * 16 + l15, ks, g);
                    fb[i] = frag_ld_f32(sH, wc + i * 16 + l15, ks, g);
                }
#pragma unroll
                for (int i = 0; i < 4; ++i)
#pragma unroll
                    for (int jj = 0; jj < 4; ++jj)
                        acc[i][jj] = __builtin_amdgcn_mfma_f32_16x16x32_bf16(
                            fa[i], fb[jj], acc[i][jj], 0, 0, 0);
            }
        }
    } else {
        size_t hoff[4];
        {
            int cb = ((lane & 7) * 16) ^ ((lane >> 3) << 4);
#pragma unroll
            for (int p = 0; p < 4; ++p) {
                int row = p * 32 + wid * 8 + (lane >> 3);
                hoff[p] = (size_t)row * HH + (cb >> 1);
            }
        }
        auto stage = [&](int tt, char* dA, char* dH) {
            int j = mi + 1 + (tt >> 1), c0 = (tt & 1) * 64;
            int offA = j * HH + c0;
#pragma unroll
            for (int i = 0; i < 8; ++i)
                gld_lds16(gA[i] + offA, dA + i * 4096 + wid * 1024);
            const unsigned short* hb =
                hmod + c_hmod_off[j] + (size_t)((t - 1) >> j) * BB * HH + c0;
#pragma unroll
            for (int p = 0; p < 4; ++p)
                gld_lds16(hb + hoff[p], dH + p * 4096 + wid * 1024);
        };
        stage(0, ldsA0, ldsH0);
        for (int tt = 0; tt < ntile; ++tt) {
            int cur = tt & 1;
            __syncthreads();
            if (tt + 1 < ntile)
                stage(tt + 1, cur ? ldsA0 : ldsA1, cur ? ldsH0 : ldsH1);
            const char* sA = cur ? ldsA1 : ldsA0;
            const char* sH = cur ? ldsH1 : ldsH0;
#pragma unroll
            for (int ks = 0; ks < 2; ++ks) {
                bf16x8 fa[4], fb[4];
#pragma unroll
                for (int i = 0; i < 4; ++i) {
                    fa[i] = frag_ld_f32(sA, wr + i * 16 + l15, ks, g);
                    fb[i] = frag_ld(sH, wc + i * 16 + l15, ks, lane);
                }
#pragma unroll
                for (int i = 0; i < 4; ++i)
#pragma unroll
                    for (int jj = 0; jj < 4; ++jj)
                        acc[i][jj] = __builtin_amdgcn_mfma_f32_16x16x32_bf16(
                            fa[i], fb[jj], acc[i][jj], 0, 0, 0);
            }
        }
    }
#pragma unroll
    for (int i = 0; i < 4; ++i) {
        int rbase = wr + i * 16 + g * 4;
#pragma unroll
        for (int j = 0; j < 4; ++j) {
            int b = wc + j * 16 + l15;
            float4* p = reinterpret_cast<float4*>(
                &xwb[(size_t)(t * BB + b) * MHW + mi * HH + rbase]);
            float4 v = *p;
            v.x += acc[i][j][0]; v.y += acc[i][j][1];
            v.z += acc[i][j][2]; v.w += acc[i][j][3];
            *p = v;
        }
    }
}

// ---------------------------------------------------------------------------
// K_s: s_{c,i} = sum_{p=0..i-1} A^{i-p} u_{8c+p} + u_{8c+i}  (f32)
// grid (C, 8) = (chunk c, i). Writes xwb cols scol=(mi+1)*HH (dead region).
// ---------------------------------------------------------------------------
__global__ __launch_bounds__(256) void k_s(const float* __restrict__ P,
                                           float* __restrict__ xwb, int mi) {
    __shared__ char lds[131072];
    char* ldsA0 = lds;
    char* ldsA1 = lds + 32768;
    char* ldsH0 = lds + 65536;
    char* ldsH1 = lds + 98304;
    int c = blockIdx.x, i = blockIdx.y;
    int tid = threadIdx.x, lane = tid & 63, wid = tid >> 6;
    int l15 = lane & 15, g = lane >> 4;
    int wr = (wid >> 1) * 64, wc = (wid & 1) * 64;
    int mcol = mi * HH, scol = (mi + 1) * HH;
    int ntile = 2 * i;
    f32x4 acc[4][4] = {};

    if (ntile > 0) {
        const float* gA[8];
        const float* gH[8];
        {
            int kb = l15 * 16;
#pragma unroll
            for (int i_ = 0; i_ < 8; ++i_) {
                int row = i_ * 16 + wid * 4 + g;
                int kf = (kb ^ ((row & 7) << 4)) >> 2;
                gA[i_] = P + (size_t)row * 128 + kf;
                gH[i_] = xwb + (size_t)row * MHW + mcol + kf;
            }
        }
        auto stage = [&](int tt, char* dA, char* dH) {
            int p = tt >> 1, c0 = (tt & 1) * 64;
            size_t offA = (size_t)(mi * 8 + (i - 1 - p)) * 16384 + c0;
            size_t offH = (size_t)((8 * c + p) << mi) * BB * MHW + c0;
#pragma unroll
            for (int i_ = 0; i_ < 8; ++i_)
                gld_lds16(gA[i_] + offA, dA + i_ * 4096 + wid * 1024);
#pragma unroll
            for (int i_ = 0; i_ < 8; ++i_)
                gld_lds16(gH[i_] + offH, dH + i_ * 4096 + wid * 1024);
        };
        stage(0, ldsA0, ldsH0);
        for (int tt = 0; tt < ntile; ++tt) {
            int cur = tt & 1;
            __syncthreads();
            if (tt + 1 < ntile)
                stage(tt + 1, cur ? ldsA0 : ldsA1, cur ? ldsH0 : ldsH1);
            const char* sA = cur ? ldsA1 : ldsA0;
            const char* sH = cur ? ldsH1 : ldsH0;
#pragma unroll
            for (int ks = 0; ks < 2; ++ks) {
                bf16x8 fa[4], fb[4];
#pragma unroll
                for (int i_ = 0; i_ < 4; ++i_) {
                    fa[i_] = frag_ld_f32(sA, wr + i_ * 16 + l15, ks, g);
                    fb[i_] = frag_ld_f32(sH, wc + i_ * 16 + l15, ks, g);
                }
#pragma unroll
                for (int i_ = 0; i_ < 4; ++i_)
#pragma unroll
                    for (int jj = 0; jj < 4; ++jj)
                        acc[i_][jj] = __builtin_amdgcn_mfma_f32_16x16x32_bf16(
                            fa[i_], fb[jj], acc[i_][jj], 0, 0, 0);
            }
        }
    }
    int tI = (8 * c + i) << mi;
#pragma unroll
    for (int i_ = 0; i_ < 4; ++i_) {
        int rbase = wr + i_ * 16 + g * 4;
#pragma unroll
        for (int j = 0; j < 4; ++j) {
            int b = wc + j * 16 + l15;
            float4 u4 = *reinterpret_cast<const float4*>(
                &xwb[(size_t)(tI * BB + b) * MHW + mcol + rbase]);
            float4 v = make_float4(acc[i_][j][0] + u4.x, acc[i_][j][1] + u4.y,
                                   acc[i_][j][2] + u4.z, acc[i_][j][3] + u4.w);
            *reinterpret_cast<float4*>(
                &xwb[(size_t)(tI * BB + b) * MHW + scol + rbase]) = v;
        }
    }
}

// ---------------------------------------------------------------------------
// K_comb: v6 k_phase with A^8, ring seeds from s (xwb scol), storer slot 8K+7.
// grid 8 x 16 batches, waves {0,1} compute, 2 producer, 3 storer.
// ---------------------------------------------------------------------------
#define SYNC_LDS()                                              \
    do {                                                        \
        asm volatile("s_waitcnt lgkmcnt(0)" ::: "memory");      \
        __builtin_amdgcn_sched_barrier(0);                      \
        __builtin_amdgcn_s_barrier();                           \
        __builtin_amdgcn_sched_barrier(0);                      \
    } while (0)
#define SYNC_VM24()                                             \
    do {                                                        \
        asm volatile("s_waitcnt vmcnt(24)" ::: "memory");       \
        __builtin_amdgcn_sched_barrier(0);                      \
        __builtin_amdgcn_s_barrier();                           \
        __builtin_amdgcn_sched_barrier(0);                      \
    } while (0)

__global__ __launch_bounds__(256) void k_comb(const float* __restrict__ P,
                                              const float* __restrict__ hprev,
                                              const float* __restrict__ xwb,
                                              unsigned short* __restrict__ hmod,
                                              int mi) {
    int b0 = blockIdx.x * 16;
    int tid = threadIdx.x, lane = tid & 63, wid = tid >> 6;
    int l15 = lane & 15, g = lane >> 4;
    __shared__ char sH[2][4096];
    __shared__ char sU[8][8192];
    int C = (TT >> mi) >> 3;
    int scol = (mi + 1) * HH;
    const float* P8 = P + (size_t)(mi * 8 + 7) * 16384;  // A^8

    if (wid < 2) {
        bf16x8 Af[4][4];
        {
#pragma unroll
            for (int mm = 0; mm < 4; ++mm) {
                const float* row = P8 + (size_t)(64 * wid + mm * 16 + l15) * 128;
#pragma unroll
                for (int kf = 0; kf < 4; ++kf) {
                    float4 v0 = *reinterpret_cast<const float4*>(row + kf * 32 + g * 8);
                    float4 v1 = *reinterpret_cast<const float4*>(row + kf * 32 + g * 8 + 4);
                    bf16x8 u;
                    u[0] = (__bf16)v0.x; u[1] = (__bf16)v0.y;
                    u[2] = (__bf16)v0.z; u[3] = (__bf16)v0.w;
                    u[4] = (__bf16)v1.x; u[5] = (__bf16)v1.y;
                    u[6] = (__bf16)v1.z; u[7] = (__bf16)v1.w;
                    Af[mm][kf] = u;
                }
            }
        }
#pragma unroll
        for (int p = 0; p < 2; ++p) {
            int tt = tid + p * 128;
            int b = tt >> 4, r8 = (tt & 15) * 8;
            const float* hp = hprev + (size_t)(b0 + b) * MHW + mi * HH + r8;
            float4 v0 = *reinterpret_cast<const float4*>(hp);
            float4 v1 = *reinterpret_cast<const float4*>(hp + 4);
            uint4 pk;
            pk.x = pack2(v0.x, v0.y); pk.y = pack2(v0.z, v0.w);
            pk.z = pack2(v1.x, v1.y); pk.w = pack2(v1.z, v1.w);
            int off = (b * 256 + r8 * 2) ^ ((b & 7) << 4);
            *reinterpret_cast<uint4*>(&sH[0][0] + off) = pk;
        }
        int roff[4], woff[4], uoff[4];
#pragma unroll
        for (int kf = 0; kf < 4; ++kf)
            roff[kf] = (l15 * 256 + kf * 64 + g * 16) ^ ((l15 & 7) << 4);
#pragma unroll
        for (int mm = 0; mm < 4; ++mm) {
            woff[mm] = (l15 * 256 + (64 * wid + mm * 16 + g * 4) * 2) ^ ((l15 & 7) << 4);
            uoff[mm] = (16 * wid + 4 * mm + g) * 256 + l15 * 16;
        }
        SYNC_LDS();

        for (int K = 0; K < C; ++K) {
            int cur = K & 1;
            const char* ub = &sU[K & 7][0];
            f32x4 acc[4], acc2[4];
#pragma unroll
            for (int mm = 0; mm < 4; ++mm) {
                acc[mm] = *reinterpret_cast<const f32x4*>(ub + uoff[mm]);
                acc2[mm] = (f32x4){0.f, 0.f, 0.f, 0.f};
            }
            bf16x8 Bf[4];
#pragma unroll
            for (int kf = 0; kf < 4; ++kf)
                Bf[kf] = *reinterpret_cast<const bf16x8*>(&sH[cur][0] + roff[kf]);
#pragma unroll
            for (int mm = 0; mm < 4; ++mm) {
                acc[mm] = __builtin_amdgcn_mfma_f32_16x16x32_bf16(
                    Af[mm][0], Bf[0], acc[mm], 0, 0, 0);
                acc2[mm] = __builtin_amdgcn_mfma_f32_16x16x32_bf16(
                    Af[mm][2], Bf[2], acc2[mm], 0, 0, 0);
                acc[mm] = __builtin_amdgcn_mfma_f32_16x16x32_bf16(
                    Af[mm][1], Bf[1], acc[mm], 0, 0, 0);
                acc2[mm] = __builtin_amdgcn_mfma_f32_16x16x32_bf16(
                    Af[mm][3], Bf[3], acc2[mm], 0, 0, 0);
            }
#pragma unroll
            for (int mm = 0; mm < 4; ++mm) {
                acc[mm] += acc2[mm];
                bf16x4 pk;
                pk[0] = (__bf16)acc[mm][0]; pk[1] = (__bf16)acc[mm][1];
                pk[2] = (__bf16)acc[mm][2]; pk[3] = (__bf16)acc[mm][3];
                *reinterpret_cast<bf16x4*>(&sH[cur ^ 1][0] + woff[mm]) = pk;
            }
            SYNC_LDS();
        }
    } else if (wid == 2) {
        const float* ubase = xwb + (size_t)(b0 + l15) * MHW + scol + g * 4;
#pragma unroll
        for (int q = 0; q < 4; ++q) {
            int t = (8 * min(q, C - 1) + 7) << mi;
            const float* pt = ubase + (size_t)t * BB * MHW;
#pragma unroll
            for (int p = 0; p < 8; ++p)
                gld_lds16(pt + p * 16, &sU[q][0] + p * 1024);
        }
        SYNC_VM24();
        for (int K = 0; K < C; ++K) {
            int t = (8 * min(K + 4, C - 1) + 7) << mi;
            int slot = (K + 4) & 7;
            const float* pt = ubase + (size_t)t * BB * MHW;
#pragma unroll
            for (int p = 0; p < 8; ++p)
                gld_lds16(pt + p * 16, &sU[slot][0] + p * 1024);
            SYNC_VM24();
        }
        asm volatile("s_waitcnt vmcnt(0)" ::: "memory");
    } else {
        int bq = lane >> 2;
        int rr = (lane & 3) * 32;
        unsigned short* hm =
            hmod + c_hmod_off[mi] + (size_t)(b0 + bq) * HH + rr;
        int soff[4];
#pragma unroll
        for (int c = 0; c < 4; ++c)
            soff[c] = (bq * 256 + (rr + c * 8) * 2) ^ ((bq & 7) << 4);
        SYNC_LDS();
        for (int K = 0; K < C; ++K) {
            if (K >= 1) {
                uint4 h[4];
#pragma unroll
                for (int c = 0; c < 4; ++c)
                    h[c] = *reinterpret_cast<const uint4*>(&sH[K & 1][0] + soff[c]);
                unsigned short* dst = hm + (size_t)(8 * (K - 1) + 7) * BB * HH;
#pragma unroll
                for (int c = 0; c < 4; ++c)
                    *reinterpret_cast<uint4*>(dst + c * 8) = h[c];
            }
            SYNC_LDS();
        }
        {
            uint4 h[4];
#pragma unroll
            for (int c = 0; c < 4; ++c)
                h[c] = *reinterpret_cast<const uint4*>(&sH[C & 1][0] + soff[c]);
            unsigned short* dst = hm + (size_t)(8 * (C - 1) + 7) * BB * HH;
#pragma unroll
            for (int c = 0; c < 4; ++c)
                *reinterpret_cast<uint4*>(dst + c * 8) = h[c];
        }
    }
}

// ---------------------------------------------------------------------------
// K_exp: h_{8c+i} = A^{i+1} bnd_{c-1} + s_{c,i}, i=0..6 -> hmod[mi].
// grid C blocks. bnd staged once (hprev f32 for c==0, hmod bf16 else);
// A staged per i (f32, single-buffered).
// ---------------------------------------------------------------------------
__global__ __launch_bounds__(256) void k_exp(const float* __restrict__ P,
                                             const float* __restrict__ hprev,
                                             const float* __restrict__ xwb,
                                             unsigned short* __restrict__ hmod,
                                             int mi) {
    __shared__ char lds[131072];
    char* sB = lds;           // bnd tiles: f32 2x32KB or bf16 2x16KB
    char* sA = lds + 65536;   // A: f32 2x32KB
    int c = blockIdx.x;
    int tid = threadIdx.x, lane = tid & 63, wid = tid >> 6;
    int l15 = lane & 15, g = lane >> 4;
    int wr = (wid >> 1) * 64, wc = (wid & 1) * 64;
    int scol = (mi + 1) * HH;
    bool bndf32 = (c == 0);

    // stage bnd (once)
    if (bndf32) {
        const float* gH[8];
        {
            int kb = l15 * 16;
#pragma unroll
            for (int i_ = 0; i_ < 8; ++i_) {
                int row = i_ * 16 + wid * 4 + g;
                int kf = (kb ^ ((row & 7) << 4)) >> 2;
                gH[i_] = hprev + (size_t)row * MHW + mi * HH + kf;
            }
        }
#pragma unroll
        for (int ck = 0; ck < 2; ++ck)
#pragma unroll
            for (int i_ = 0; i_ < 8; ++i_)
                gld_lds16(gH[i_] + ck * 64, sB + ck * 32768 + i_ * 4096 + wid * 1024);
    } else {
        size_t hoff[4];
        {
            int cb = ((lane & 7) * 16) ^ ((lane >> 3) << 4);
#pragma unroll
            for (int p = 0; p < 4; ++p) {
                int row = p * 32 + wid * 8 + (lane >> 3);
                hoff[p] = (size_t)row * HH + (cb >> 1);
            }
        }
        const unsigned short* hb =
            hmod + c_hmod_off[mi] + (size_t)(8 * (c - 1) + 7) * BB * HH;
#pragma unroll
        for (int ck = 0; ck < 2; ++ck)
#pragma unroll
            for (int p = 0; p < 4; ++p)
                gld_lds16(hb + ck * 64 + hoff[p],
                          sB + ck * 16384 + p * 4096 + wid * 1024);
    }
    const float* gA[8];
    {
        int kb = l15 * 16;
#pragma unroll
        for (int i_ = 0; i_ < 8; ++i_) {
            int row = i_ * 16 + wid * 4 + g;
            int kf = (kb ^ ((row & 7) << 4)) >> 2;
            gA[i_] = P + (size_t)row * 128 + kf;
        }
    }

    for (int i = 0; i < 7; ++i) {
        __syncthreads();  // prev compute done (and bnd/gld staged on first iter)
        {
            size_t offA = (size_t)(mi * 8 + i) * 16384;  // A^{i+1}
#pragma unroll
            for (int ck = 0; ck < 2; ++ck)
#pragma unroll
                for (int i_ = 0; i_ < 8; ++i_)
                    gld_lds16(gA[i_] + offA + ck * 64,
                              sA + ck * 32768 + i_ * 4096 + wid * 1024);
        }
        __syncthreads();  // staging complete
        f32x4 acc[4][4] = {};
#pragma unroll
        for (int ck = 0; ck < 2; ++ck) {
#pragma unroll
            for (int ks = 0; ks < 2; ++ks) {
                bf16x8 fa[4], fb[4];
#pragma unroll
                for (int i_ = 0; i_ < 4; ++i_) {
                    fa[i_] = frag_ld_f32(sA + ck * 32768, wr + i_ * 16 + l15, ks, g);
                    fb[i_] = bndf32
                        ? frag_ld_f32(sB + ck * 32768, wc + i_ * 16 + l15, ks, g)
                        : frag_ld(sB + ck * 16384, wc + i_ * 16 + l15, ks, lane);
                }
#pragma unroll
                for (int i_ = 0; i_ < 4; ++i_)
#pragma unroll
                    for (int jj = 0; jj < 4; ++jj)
                        acc[i_][jj] = __builtin_amdgcn_mfma_f32_16x16x32_bf16(
                            fa[i_], fb[jj], acc[i_][jj], 0, 0, 0);
            }
        }
        int tI = (8 * c + i) << mi;
#pragma unroll
        for (int i_ = 0; i_ < 4; ++i_) {
            int rbase = wr + i_ * 16 + g * 4;
#pragma unroll
            for (int j = 0; j < 4; ++j) {
                int b = wc + j * 16 + l15;
                float4 s4 = *reinterpret_cast<const float4*>(
                    &xwb[(size_t)(tI * BB + b) * MHW + scol + rbase]);
                uint2 pk;
                pk.x = pack2(acc[i_][j][0] + s4.x, acc[i_][j][1] + s4.y);
                pk.y = pack2(acc[i_][j][2] + s4.z, acc[i_][j][3] + s4.w);
                *reinterpret_cast<uint2*>(
                    &hmod[c_hmod_off[mi] + ((size_t)(8 * c + i) * BB + b) * HH +
                          rbase]) = pk;
            }
        }
    }
}

// ---------------------------------------------------------------------------
// K_phase (R13 v6, unchanged — used for mi >= 2)
// ---------------------------------------------------------------------------
__global__ __launch_bounds__(256) void k_phase(const float* __restrict__ Whh,
                                               const float* __restrict__ hprev,
                                               const float* __restrict__ xwb,
                                               unsigned short* __restrict__ hmod,
                                               int mi) {
    int b0 = blockIdx.x * 16;
    int tid = threadIdx.x, lane = tid & 63, wid = tid >> 6;
    int l15 = lane & 15, g = lane >> 4;
    __shared__ char sH[2][4096];
    __shared__ char sU[8][8192];
    int Tm = TT >> mi;

    if (wid < 2) {
        bf16x8 Af[4][4];
        {
            const float* Ab = Whh + (size_t)(mi * HH) * MHW + mi * HH;
#pragma unroll
            for (int mm = 0; mm < 4; ++mm) {
                const float* row = Ab + (size_t)(64 * wid + mm * 16 + l15) * MHW;
#pragma unroll
                for (int kf = 0; kf < 4; ++kf) {
                    float4 v0 = *reinterpret_cast<const float4*>(row + kf * 32 + g * 8);
                    float4 v1 = *reinterpret_cast<const float4*>(row + kf * 32 + g * 8 + 4);
                    bf16x8 u;
                    u[0] = (__bf16)v0.x; u[1] = (__bf16)v0.y;
                    u[2] = (__bf16)v0.z; u[3] = (__bf16)v0.w;
                    u[4] = (__bf16)v1.x; u[5] = (__bf16)v1.y;
                    u[6] = (__bf16)v1.z; u[7] = (__bf16)v1.w;
                    Af[mm][kf] = u;
                }
            }
        }
#pragma unroll
        for (int p = 0; p < 2; ++p) {
            int tt = tid + p * 128;
            int b = tt >> 4, r8 = (tt & 15) * 8;
            const float* hp = hprev + (size_t)(b0 + b) * MHW + mi * HH + r8;
            float4 v0 = *reinterpret_cast<const float4*>(hp);
            float4 v1 = *reinterpret_cast<const float4*>(hp + 4);
            uint4 pk;
            pk.x = pack2(v0.x, v0.y); pk.y = pack2(v0.z, v0.w);
            pk.z = pack2(v1.x, v1.y); pk.w = pack2(v1.z, v1.w);
            int off = (b * 256 + r8 * 2) ^ ((b & 7) << 4);
            *reinterpret_cast<uint4*>(&sH[0][0] + off) = pk;
        }
        int roff[4], woff[4], uoff[4];
#pragma unroll
        for (int kf = 0; kf < 4; ++kf)
            roff[kf] = (l15 * 256 + kf * 64 + g * 16) ^ ((l15 & 7) << 4);
#pragma unroll
        for (int mm = 0; mm < 4; ++mm) {
            woff[mm] = (l15 * 256 + (64 * wid + mm * 16 + g * 4) * 2) ^ ((l15 & 7) << 4);
            uoff[mm] = (16 * wid + 4 * mm + g) * 256 + l15 * 16;
        }
        SYNC_LDS();

        for (int K = 0; K < Tm; ++K) {
            int cur = K & 1;
            const char* ub = &sU[K & 7][0];
            f32x4 acc[4], acc2[4];
#pragma unroll
            for (int mm = 0; mm < 4; ++mm) {
                acc[mm] = *reinterpret_cast<const f32x4*>(ub + uoff[mm]);
                acc2[mm] = (f32x4){0.f, 0.f, 0.f, 0.f};
            }
            bf16x8 Bf[4];
#pragma unroll
            for (int kf = 0; kf < 4; ++kf)
                Bf[kf] = *reinterpret_cast<const bf16x8*>(&sH[cur][0] + roff[kf]);
#pragma unroll
            for (int mm = 0; mm < 4; ++mm) {
                acc[mm] = __builtin_amdgcn_mfma_f32_16x16x32_bf16(
                    Af[mm][0], Bf[0], acc[mm], 0, 0, 0);
                acc2[mm] = __builtin_amdgcn_mfma_f32_16x16x32_bf16(
                    Af[mm][2], Bf[2], acc2[mm], 0, 0, 0);
                acc[mm] = __builtin_amdgcn_mfma_f32_16x16x32_bf16(
                    Af[mm][1], Bf[1], acc[mm], 0, 0, 0);
                acc2[mm] = __builtin_amdgcn_mfma_f32_16x16x32_bf16(
                    Af[mm][3], Bf[3], acc2[mm], 0, 0, 0);
            }
#pragma unroll
            for (int mm = 0; mm < 4; ++mm) {
                acc[mm] += acc2[mm];
                bf16x4 pk;
                pk[0] = (__bf16)acc[mm][0]; pk[1] = (__bf16)acc[mm][1];
                pk[2] = (__bf16)acc[mm][2]; pk[3] = (__bf16)acc[mm][3];
                *reinterpret_cast<bf16x4*>(&sH[cur ^ 1][0] + woff[mm]) = pk;
            }
            SYNC_LDS();
        }
    } else if (wid == 2) {
        const float* ubase = xwb + (size_t)(b0 + l15) * MHW + mi * HH + g * 4;
#pragma unroll
        for (int q = 0; q < 4; ++q) {
            int t = min(q, Tm - 1) << mi;
            const float* pt = ubase + (size_t)t * BB * MHW;
#pragma unroll
            for (int p = 0; p < 8; ++p)
                gld_lds16(pt + p * 16, &sU[q][0] + p * 1024);
        }
        SYNC_VM24();
        for (int K = 0; K < Tm; ++K) {
            int t = min(K + 4, Tm - 1) << mi;
            int slot = (K + 4) & 7;
            const float* pt = ubase + (size_t)t * BB * MHW;
#pragma unroll
            for (int p = 0; p < 8; ++p)
                gld_lds16(pt + p * 16, &sU[slot][0] + p * 1024);
            SYNC_VM24();
        }
        asm volatile("s_waitcnt vmcnt(0)" ::: "memory");
    } else {
        int bq = lane >> 2;
        int rr = (lane & 3) * 32;
        unsigned short* hm =
            hmod + c_hmod_off[mi] + (size_t)(b0 + bq) * HH + rr;
        int soff[4];
#pragma unroll
        for (int c = 0; c < 4; ++c)
            soff[c] = (bq * 256 + (rr + c * 8) * 2) ^ ((bq & 7) << 4);
        SYNC_LDS();
        for (int K = 0; K < Tm; ++K) {
            if (K >= 1) {
                uint4 h[4];
#pragma unroll
                for (int c = 0; c < 4; ++c)
                    h[c] = *reinterpret_cast<const uint4*>(&sH[K & 1][0] + soff[c]);
                unsigned short* dst = hm + (size_t)(K - 1) * BB * HH;
#pragma unroll
                for (int c = 0; c < 4; ++c)
                    *reinterpret_cast<uint4*>(dst + c * 8) = h[c];
            }
            SYNC_LDS();
        }
        {
            uint4 h[4];
#pragma unroll
            for (int c = 0; c < 4; ++c)
                h[c] = *reinterpret_cast<const uint4*>(&sH[Tm & 1][0] + soff[c]);
            unsigned short* dst = hm + (size_t)(Tm - 1) * BB * HH;
#pragma unroll
            for (int c = 0; c < 4; ++c)
                *reinterpret_cast<uint4*>(dst + c * 8) = h[c];
        }
    }
}

// ---------------------------------------------------------------------------
// K_out (unchanged)
// ---------------------------------------------------------------------------
__global__ __launch_bounds__(256) void k_out(const unsigned short* __restrict__ hmod,
                                             float* __restrict__ out) {
    int b = blockIdx.x, t = blockIdx.y;
    int tid = threadIdx.x;
    int i = tid * 4;
    int j = i >> 7;
    int k = t >> j;
    ushort4 h = *reinterpret_cast<const ushort4*>(
        &hmod[c_hmod_off[j] + ((size_t)k * BB + b) * HH + (i & 127)]);
    float4 v = make_float4(bf2f(h.x), bf2f(h.y), bf2f(h.z), bf2f(h.w));
    *reinterpret_cast<float4*>(&out[((size_t)t * BB + b) * MHW + i]) = v;
    if (t == TT - 1) {
        *reinterpret_cast<float4*>(
            &out[(size_t)TT * BB * MHW + (size_t)b * MHW + i]) = v;
    }
}

// ---------------------------------------------------------------------------
extern "C" void kernel_launch(void* const* d_in, const int* in_sizes, int n_in,
                              void* d_out, int out_size, void* d_ws, size_t ws_size,
                              hipStream_t stream) {
    const float* x = (const float*)d_in[0];
    const float* hprev = (const float*)d_in[1];
    const float* Wxh = (const float*)d_in[2];
    const float* Whh = (const float*)d_in[3];
    const float* bh = (const float*)d_in[4];
    float* out = (float*)d_out;

    float* xwb = out;                              // scratch in d_out
    unsigned short* hmod = (unsigned short*)d_ws;  // bf16, 16.7 MB
    float* P = (float*)((char*)d_ws + 16711680);   // A-powers, 1 MB

    k_xw<<<dim3(1020), 256, 0, stream>>>(x, Wxh, bh, xwb);
    k_pow<<<dim3(2), 256, 0, stream>>>(Whh, P);

    for (int mi = 7; mi >= 2; --mi) {
        if (mi < 7)
            k_u<<<dim3(TT >> mi), 256, 0, stream>>>(Whh, hprev, hmod, xwb, mi);
        k_phase<<<8, 256, 0, stream>>>(Whh, hprev, xwb, hmod, mi);
    }
    for (int mi = 1; mi >= 0; --mi) {
        int C = (TT >> mi) >> 3;
        k_u<<<dim3(TT >> mi), 256, 0, stream>>>(Whh, hprev, hmod, xwb, mi);
        k_s<<<dim3(C, 8), 256, 0, stream>>>(P, xwb, mi);
        k_comb<<<8, 256, 0, stream>>>(P, hprev, xwb, hmod, mi);
        k_exp<<<dim3(C), 256, 0, stream>>>(P, hprev, xwb, hmod, mi);
    }

    k_out<<<dim3(128, 256), 256, 0, stream>>>(hmod, out);
}

// Round 18
// 384.279 us; speedup vs baseline: 1.1418x; 1.1418x over previous
//
#include <hip/hip_runtime.h>
#include <hip/hip_bf16.h>

// Clockwork RNN, hierarchical decomposition + bf16 MFMA GEMMs.
// Round 18: R13 base (scan structure banked at 404 us) + k_xw v4:
//   K-chunk 64 -> 32 so LDS 96KB -> 48KB => 3 blocks/CU (was 1).
//   Cross-block TLP hides the per-chunk vmcnt(0) barrier drains that
//   serialized k_xw at 1 block/CU. Same staging scheme (gld_lds f32,
//   pre-swizzled sources, cvt-on-read fragments), 16 chunks of K=32.
// k_u / k_phase (v6) / k_out unchanged from R13.

#define TT 256
#define BB 128
#define INW 512
#define HH 128
#define MHW 1024

typedef __bf16 bf16x8 __attribute__((ext_vector_type(8)));
typedef __bf16 bf16x4 __attribute__((ext_vector_type(4)));
typedef float f32x4 __attribute__((ext_vector_type(4)));

__constant__ unsigned int c_hmod_off[8] = {
    0u, 4194304u, 6291456u, 7340032u, 7864320u, 8126464u, 8257536u, 8323072u};

__device__ __forceinline__ unsigned short f2bf(float f) {
    union { float f; unsigned int u; } v{f};
    unsigned int r = v.u + 0x7FFFu + ((v.u >> 16) & 1u);  // RNE
    return (unsigned short)(r >> 16);
}
__device__ __forceinline__ unsigned int pack2(float lo, float hi) {
    return (unsigned int)f2bf(lo) | ((unsigned int)f2bf(hi) << 16);
}
__device__ __forceinline__ float bf2f(unsigned short u) {
    union { unsigned int i; float f; } v;
    v.i = ((unsigned int)u) << 16;
    return v.f;
}

__device__ __forceinline__ void gld_lds16(const void* g, char* l) {
    __builtin_amdgcn_global_load_lds(
        (const __attribute__((address_space(1))) void*)g,
        (__attribute__((address_space(3))) void*)l, 16, 0, 0);
}

// Read one 16x32 bf16 fragment (8 bf16) from a swizzled bf16 tile ([rows][64] bf16).
__device__ __forceinline__ bf16x8 frag_ld(const char* tile, int row, int ks, int lane) {
    int off = (row * 128 + ks * 64 + (lane >> 4) * 16) ^ ((row & 7) << 4);
    return *reinterpret_cast<const bf16x8*>(tile + off);
}

// Read one fragment from a swizzled f32 tile with 256B rows ([rows][64] f32).
__device__ __forceinline__ bf16x8 frag_ld_f32(const char* tile, int row, int ks, int g) {
    int off = ((row << 8) + ks * 128 + g * 32) ^ ((row & 7) << 4);
    f32x4 a = *reinterpret_cast<const f32x4*>(tile + off);
    f32x4 b = *reinterpret_cast<const f32x4*>(tile + (off ^ 16));
    bf16x8 u;
    u[0] = (__bf16)a[0]; u[1] = (__bf16)a[1]; u[2] = (__bf16)a[2]; u[3] = (__bf16)a[3];
    u[4] = (__bf16)b[0]; u[5] = (__bf16)b[1]; u[6] = (__bf16)b[2]; u[7] = (__bf16)b[3];
    return u;
}

// Read one fragment from a swizzled f32 tile with 128B rows ([rows][32] f32).
__device__ __forceinline__ bf16x8 frag_ld_f32_k32(const char* tile, int row, int g) {
    int off = ((row << 7) + g * 32) ^ ((row & 7) << 4);
    f32x4 a = *reinterpret_cast<const f32x4*>(tile + off);
    f32x4 b = *reinterpret_cast<const f32x4*>(tile + (off ^ 16));
    bf16x8 u;
    u[0] = (__bf16)a[0]; u[1] = (__bf16)a[1]; u[2] = (__bf16)a[2]; u[3] = (__bf16)a[3];
    u[4] = (__bf16)b[0]; u[5] = (__bf16)b[1]; u[6] = (__bf16)b[2]; u[7] = (__bf16)b[3];
    return u;
}

// ---------------------------------------------------------------------------
// K_xw v4: 1020 blocks = 510 active (t, rt) x 2 batch-halves. 16 chunks of
// K=32; LDS 48KB (3 blocks/CU). gld_lds f32 staging, pre-swizzled sources.
// ---------------------------------------------------------------------------
__global__ __launch_bounds__(256) void k_xw(const float* __restrict__ x,
                                            const float* __restrict__ Wxh,
                                            const float* __restrict__ bh,
                                            float* __restrict__ xwb) {
    __shared__ char ldsW[2][16384];  // [128 rows][32 f32], 128B rows
    __shared__ char ldsX[2][8192];   // [64 rows][32 f32]
    int id = blockIdx.x >> 1, half = blockIdx.x & 1;
    int rt = 0, rem = id;
    while (rem >= (256 >> rt)) { rem -= 256 >> rt; ++rt; }
    int t = rem << rt;

    int tid = threadIdx.x, lane = tid & 63, wid = tid >> 6;
    int l15 = lane & 15, g = lane >> 4;
    int wr = (wid >> 1) * 64, wc = (wid & 1) * 32;

    // Pre-swizzled per-lane sources (128B-row tiles): instr p covers rows
    // p*32 + wid*8 + (lane>>3); lane's 16B slab at col (lane&7)*16 ^ swz.
    const float* gW[4];
    const float* gX[2];
    {
        int kb = (lane & 7) * 16;
#pragma unroll
        for (int p = 0; p < 4; ++p) {
            int row = p * 32 + wid * 8 + (lane >> 3);
            int kf = (kb ^ ((row & 7) << 4)) >> 2;
            gW[p] = Wxh + (size_t)(rt * 128 + row) * INW + kf;
        }
#pragma unroll
        for (int p = 0; p < 2; ++p) {
            int row = p * 32 + wid * 8 + (lane >> 3);
            int kf = (kb ^ ((row & 7) << 4)) >> 2;
            gX[p] = x + ((size_t)t * BB + half * 64 + row) * INW + kf;
        }
    }
    // prologue: stage chunk 0 into buf 0
#pragma unroll
    for (int p = 0; p < 4; ++p)
        gld_lds16(gW[p], &ldsW[0][0] + p * 4096 + wid * 1024);
#pragma unroll
    for (int p = 0; p < 2; ++p)
        gld_lds16(gX[p], &ldsX[0][0] + p * 4096 + wid * 1024);

    f32x4 acc[4][2] = {};
    for (int c = 0; c < 16; ++c) {
        int cur = c & 1;
        __syncthreads();  // buf[cur] ready (drains gld_lds)
        if (c < 15) {
#pragma unroll
            for (int p = 0; p < 4; ++p)
                gld_lds16(gW[p] + (c + 1) * 32,
                          &ldsW[cur ^ 1][0] + p * 4096 + wid * 1024);
#pragma unroll
            for (int p = 0; p < 2; ++p)
                gld_lds16(gX[p] + (c + 1) * 32,
                          &ldsX[cur ^ 1][0] + p * 4096 + wid * 1024);
        }
        bf16x8 fa[4], fb[2];
#pragma unroll
        for (int i = 0; i < 4; ++i)
            fa[i] = frag_ld_f32_k32(&ldsW[cur][0], wr + i * 16 + l15, g);
#pragma unroll
        for (int j = 0; j < 2; ++j)
            fb[j] = frag_ld_f32_k32(&ldsX[cur][0], wc + j * 16 + l15, g);
#pragma unroll
        for (int i = 0; i < 4; ++i)
#pragma unroll
            for (int j = 0; j < 2; ++j)
                acc[i][j] = __builtin_amdgcn_mfma_f32_16x16x32_bf16(
                    fa[i], fb[j], acc[i][j], 0, 0, 0);
    }
    // epilogue: bias + store
#pragma unroll
    for (int i = 0; i < 4; ++i) {
        int rbase = rt * 128 + wr + i * 16 + g * 4;
        float4 bias = *reinterpret_cast<const float4*>(&bh[rbase]);
#pragma unroll
        for (int j = 0; j < 2; ++j) {
            int b = half * 64 + wc + j * 16 + l15;
            float4 v = make_float4(acc[i][j][0] + bias.x, acc[i][j][1] + bias.y,
                                   acc[i][j][2] + bias.z, acc[i][j][3] + bias.w);
            *reinterpret_cast<float4*>(
                &xwb[(size_t)(t * BB + b) * MHW + rbase]) = v;
        }
    }
}

// ---------------------------------------------------------------------------
// K_u (unchanged R13): gld_lds staging for A (f32) and H (hprev f32 / hmod bf16).
// ---------------------------------------------------------------------------
__global__ __launch_bounds__(256) void k_u(const float* __restrict__ Whh,
                                           const float* __restrict__ hprev,
                                           const unsigned short* __restrict__ hmod,
                                           float* __restrict__ xwb, int mi) {
    __shared__ char lds[131072];
    char* ldsA0 = lds;
    char* ldsA1 = lds + 32768;
    char* ldsH0 = lds + 65536;
    char* ldsH1 = lds + 98304;
    int k = blockIdx.x;
    int t = k << mi;
    int tid = threadIdx.x, lane = tid & 63, wid = tid >> 6;
    int l15 = lane & 15, g = lane >> 4;
    int wr = (wid >> 1) * 64, wc = (wid & 1) * 64;
    int ntile = 2 * (7 - mi);

    const float* gA[8];
    {
        int kb = l15 * 16;
#pragma unroll
        for (int i = 0; i < 8; ++i) {
            int row = i * 16 + wid * 4 + g;
            int kf = (kb ^ ((row & 7) << 4)) >> 2;
            gA[i] = Whh + (size_t)(mi * HH + row) * MHW + kf;
        }
    }
    f32x4 acc[4][4] = {};

    if (k == 0) {
        const float* gH[8];
        {
            int kb = l15 * 16;
#pragma unroll
            for (int i = 0; i < 8; ++i) {
                int row = i * 16 + wid * 4 + g;
                int kf = (kb ^ ((row & 7) << 4)) >> 2;
                gH[i] = hprev + (size_t)row * MHW + kf;
            }
        }
        auto stage = [&](int tt, char* dA, char* dH) {
            int j = mi + 1 + (tt >> 1), c0 = (tt & 1) * 64;
            int off = j * HH + c0;
#pragma unroll
            for (int i = 0; i < 8; ++i)
                gld_lds16(gA[i] + off, dA + i * 4096 + wid * 1024);
#pragma unroll
            for (int i = 0; i < 8; ++i)
                gld_lds16(gH[i] + off, dH + i * 4096 + wid * 1024);
        };
        stage(0, ldsA0, ldsH0);
        for (int tt = 0; tt < ntile; ++tt) {
            int cur = tt & 1;
            __syncthreads();
            if (tt + 1 < ntile)
                stage(tt + 1, cur ? ldsA0 : ldsA1, cur ? ldsH0 : ldsH1);
            const char* sA = cur ? ldsA1 : ldsA0;
            const char* sH = cur ? ldsH1 : ldsH0;
#pragma unroll
            for (int ks = 0; ks < 2; ++ks) {
                bf16x8 fa[4], fb[4];
#pragma unroll
                for (int i = 0; i < 4; ++i) {
                    fa[i] = frag_ld_f32(sA, wr + i * 16 + l15, ks, g);
                    fb[i] = frag_ld_f32(sH, wc + i * 16 + l15, ks, g);
                }
#pragma unroll
                for (int i = 0; i < 4; ++i)
#pragma unroll
                    for (int jj = 0; jj < 4; ++jj)
                        acc[i][jj] = __builtin_amdgcn_mfma_f32_16x16x32_bf16(
                            fa[i], fb[jj], acc[i][jj], 0, 0, 0);
            }
        }
    } else {
        size_t hoff[4];
        {
            int cb = ((lane & 7) * 16) ^ ((lane >> 3) << 4);
#pragma unroll
            for (int p = 0; p < 4; ++p) {
                int row = p * 32 + wid * 8 + (lane >> 3);
                hoff[p] = (size_t)row * HH + (cb >> 1);
            }
        }
        auto stage = [&](int tt, char* dA, char* dH) {
            int j = mi + 1 + (tt >> 1), c0 = (tt & 1) * 64;
            int offA = j * HH + c0;
#pragma unroll
            for (int i = 0; i < 8; ++i)
                gld_lds16(gA[i] + offA, dA + i * 4096 + wid * 1024);
            const unsigned short* hb =
                hmod + c_hmod_off[j] + (size_t)((t - 1) >> j) * BB * HH + c0;
#pragma unroll
            for (int p = 0; p < 4; ++p)
                gld_lds16(hb + hoff[p], dH + p * 4096 + wid * 1024);
        };
        stage(0, ldsA0, ldsH0);
        for (int tt = 0; tt < ntile; ++tt) {
            int cur = tt & 1;
            __syncthreads();
            if (tt + 1 < ntile)
                stage(tt + 1, cur ? ldsA0 : ldsA1, cur ? ldsH0 : ldsH1);
            const char* sA = cur ? ldsA1 : ldsA0;
            const char* sH = cur ? ldsH1 : ldsH0;
#pragma unroll
            for (int ks = 0; ks < 2; ++ks) {
                bf16x8 fa[4], fb[4];
#pragma unroll
                for (int i = 0; i < 4; ++i) {
                    fa[i] = frag_ld_f32(sA, wr + i * 16 + l15, ks, g);
                    fb[i] = frag_ld(sH, wc + i * 16 + l15, ks, lane);
                }
#pragma unroll
                for (int i = 0; i < 4; ++i)
#pragma unroll
                    for (int jj = 0; jj < 4; ++jj)
                        acc[i][jj] = __builtin_amdgcn_mfma_f32_16x16x32_bf16(
                            fa[i], fb[jj], acc[i][jj], 0, 0, 0);
            }
        }
    }
#pragma unroll
    for (int i = 0; i < 4; ++i) {
        int rbase = wr + i * 16 + g * 4;
#pragma unroll
        for (int j = 0; j < 4; ++j) {
            int b = wc + j * 16 + l15;
            float4* p = reinterpret_cast<float4*>(
                &xwb[(size_t)(t * BB + b) * MHW + mi * HH + rbase]);
            float4 v = *p;
            v.x += acc[i][j][0]; v.y += acc[i][j][1];
            v.z += acc[i][j][2]; v.w += acc[i][j][3];
            *p = v;
        }
    }
}

// ---------------------------------------------------------------------------
// K_phase v6 (R13, verified): wave-specialized MFMA scan. 8 blocks x 16
// batches, 256 thr = waves {0,1}: compute, 2: u-producer, 3: h-storer.
// ---------------------------------------------------------------------------
#define SYNC_LDS()                                              \
    do {                                                        \
        asm volatile("s_waitcnt lgkmcnt(0)" ::: "memory");      \
        __builtin_amdgcn_sched_barrier(0);                      \
        __builtin_amdgcn_s_barrier();                           \
        __builtin_amdgcn_sched_barrier(0);                      \
    } while (0)
#define SYNC_VM24()                                             \
    do {                                                        \
        asm volatile("s_waitcnt vmcnt(24)" ::: "memory");       \
        __builtin_amdgcn_sched_barrier(0);                      \
        __builtin_amdgcn_s_barrier();                           \
        __builtin_amdgcn_sched_barrier(0);                      \
    } while (0)

__global__ __launch_bounds__(256) void k_phase(const float* __restrict__ Whh,
                                               const float* __restrict__ hprev,
                                               const float* __restrict__ xwb,
                                               unsigned short* __restrict__ hmod,
                                               int mi) {
    int b0 = blockIdx.x * 16;
    int tid = threadIdx.x, lane = tid & 63, wid = tid >> 6;
    int l15 = lane & 15, g = lane >> 4;
    __shared__ char sH[2][4096];   // [buf][b][r] bf16, swizzled
    __shared__ char sU[8][8192];   // u ring: [slot][r/4][b][4xf32], linear
    int Tm = TT >> mi;

    if (wid < 2) {
        // ================= compute waves =================
        bf16x8 Af[4][4];
        {
            const float* Ab = Whh + (size_t)(mi * HH) * MHW + mi * HH;
#pragma unroll
            for (int mm = 0; mm < 4; ++mm) {
                const float* row = Ab + (size_t)(64 * wid + mm * 16 + l15) * MHW;
#pragma unroll
                for (int kf = 0; kf < 4; ++kf) {
                    float4 v0 = *reinterpret_cast<const float4*>(row + kf * 32 + g * 8);
                    float4 v1 = *reinterpret_cast<const float4*>(row + kf * 32 + g * 8 + 4);
                    bf16x8 u;
                    u[0] = (__bf16)v0.x; u[1] = (__bf16)v0.y;
                    u[2] = (__bf16)v0.z; u[3] = (__bf16)v0.w;
                    u[4] = (__bf16)v1.x; u[5] = (__bf16)v1.y;
                    u[6] = (__bf16)v1.z; u[7] = (__bf16)v1.w;
                    Af[mm][kf] = u;
                }
            }
        }
        // initial H into buf 0 (tid 0..127 cover 16 batches x 128 rows)
#pragma unroll
        for (int p = 0; p < 2; ++p) {
            int tt = tid + p * 128;
            int b = tt >> 4, r8 = (tt & 15) * 8;
            const float* hp = hprev + (size_t)(b0 + b) * MHW + mi * HH + r8;
            float4 v0 = *reinterpret_cast<const float4*>(hp);
            float4 v1 = *reinterpret_cast<const float4*>(hp + 4);
            uint4 pk;
            pk.x = pack2(v0.x, v0.y); pk.y = pack2(v0.z, v0.w);
            pk.z = pack2(v1.x, v1.y); pk.w = pack2(v1.z, v1.w);
            int off = (b * 256 + r8 * 2) ^ ((b & 7) << 4);
            *reinterpret_cast<uint4*>(&sH[0][0] + off) = pk;
        }
        int roff[4], woff[4], uoff[4];
#pragma unroll
        for (int kf = 0; kf < 4; ++kf)
            roff[kf] = (l15 * 256 + kf * 64 + g * 16) ^ ((l15 & 7) << 4);
#pragma unroll
        for (int mm = 0; mm < 4; ++mm) {
            woff[mm] = (l15 * 256 + (64 * wid + mm * 16 + g * 4) * 2) ^ ((l15 & 7) << 4);
            uoff[mm] = (16 * wid + 4 * mm + g) * 256 + l15 * 16;
        }
        SYNC_LDS();

        for (int K = 0; K < Tm; ++K) {
            int cur = K & 1;
            const char* ub = &sU[K & 7][0];
            f32x4 acc[4], acc2[4];
#pragma unroll
            for (int mm = 0; mm < 4; ++mm) {
                acc[mm] = *reinterpret_cast<const f32x4*>(ub + uoff[mm]);
                acc2[mm] = (f32x4){0.f, 0.f, 0.f, 0.f};
            }
            bf16x8 Bf[4];
#pragma unroll
            for (int kf = 0; kf < 4; ++kf)
                Bf[kf] = *reinterpret_cast<const bf16x8*>(&sH[cur][0] + roff[kf]);
#pragma unroll
            for (int mm = 0; mm < 4; ++mm) {
                acc[mm] = __builtin_amdgcn_mfma_f32_16x16x32_bf16(
                    Af[mm][0], Bf[0], acc[mm], 0, 0, 0);
                acc2[mm] = __builtin_amdgcn_mfma_f32_16x16x32_bf16(
                    Af[mm][2], Bf[2], acc2[mm], 0, 0, 0);
                acc[mm] = __builtin_amdgcn_mfma_f32_16x16x32_bf16(
                    Af[mm][1], Bf[1], acc[mm], 0, 0, 0);
                acc2[mm] = __builtin_amdgcn_mfma_f32_16x16x32_bf16(
                    Af[mm][3], Bf[3], acc2[mm], 0, 0, 0);
            }
#pragma unroll
            for (int mm = 0; mm < 4; ++mm) {
                acc[mm] += acc2[mm];
                bf16x4 pk;
                pk[0] = (__bf16)acc[mm][0]; pk[1] = (__bf16)acc[mm][1];
                pk[2] = (__bf16)acc[mm][2]; pk[3] = (__bf16)acc[mm][3];
                *reinterpret_cast<bf16x4*>(&sH[cur ^ 1][0] + woff[mm]) = pk;
            }
            SYNC_LDS();
        }
    } else if (wid == 2) {
        // ================= u producer =================
        const float* ubase = xwb + (size_t)(b0 + l15) * MHW + mi * HH + g * 4;
#pragma unroll
        for (int q = 0; q < 4; ++q) {  // prologue: slots 0..3
            int t = min(q, Tm - 1) << mi;
            const float* pt = ubase + (size_t)t * BB * MHW;
#pragma unroll
            for (int p = 0; p < 8; ++p)
                gld_lds16(pt + p * 16, &sU[q][0] + p * 1024);
        }
        SYNC_VM24();  // retires slot 0
        for (int K = 0; K < Tm; ++K) {
            int t = min(K + 4, Tm - 1) << mi;
            int slot = (K + 4) & 7;
            const float* pt = ubase + (size_t)t * BB * MHW;
#pragma unroll
            for (int p = 0; p < 8; ++p)
                gld_lds16(pt + p * 16, &sU[slot][0] + p * 1024);
            SYNC_VM24();  // retires slot K+1 (needed next step)
        }
        asm volatile("s_waitcnt vmcnt(0)" ::: "memory");
    } else {
        // ================= h storer =================
        int bq = lane >> 2;
        int rr = (lane & 3) * 32;
        unsigned short* hm =
            hmod + c_hmod_off[mi] + (size_t)(b0 + bq) * HH + rr;
        int soff[4];
#pragma unroll
        for (int c = 0; c < 4; ++c)
            soff[c] = (bq * 256 + (rr + c * 8) * 2) ^ ((bq & 7) << 4);
        SYNC_LDS();
        for (int K = 0; K < Tm; ++K) {
            if (K >= 1) {
                uint4 h[4];
#pragma unroll
                for (int c = 0; c < 4; ++c)
                    h[c] = *reinterpret_cast<const uint4*>(&sH[K & 1][0] + soff[c]);
                unsigned short* dst = hm + (size_t)(K - 1) * BB * HH;
#pragma unroll
                for (int c = 0; c < 4; ++c)
                    *reinterpret_cast<uint4*>(dst + c * 8) = h[c];
            }
            SYNC_LDS();
        }
        {  // final state s_Tm -> hmod[Tm-1]
            uint4 h[4];
#pragma unroll
            for (int c = 0; c < 4; ++c)
                h[c] = *reinterpret_cast<const uint4*>(&sH[Tm & 1][0] + soff[c]);
            unsigned short* dst = hm + (size_t)(Tm - 1) * BB * HH;
#pragma unroll
            for (int c = 0; c < 4; ++c)
                *reinterpret_cast<uint4*>(dst + c * 8) = h[c];
        }
    }
}

// ---------------------------------------------------------------------------
// K_out (unchanged): out[t][b][j*H + h] = bf2f(Hmod[j][t>>j][b][h]); h_last.
// ---------------------------------------------------------------------------
__global__ __launch_bounds__(256) void k_out(const unsigned short* __restrict__ hmod,
                                             float* __restrict__ out) {
    int b = blockIdx.x, t = blockIdx.y;
    int tid = threadIdx.x;
    int i = tid * 4;
    int j = i >> 7;
    int k = t >> j;
    ushort4 h = *reinterpret_cast<const ushort4*>(
        &hmod[c_hmod_off[j] + ((size_t)k * BB + b) * HH + (i & 127)]);
    float4 v = make_float4(bf2f(h.x), bf2f(h.y), bf2f(h.z), bf2f(h.w));
    *reinterpret_cast<float4*>(&out[((size_t)t * BB + b) * MHW + i]) = v;
    if (t == TT - 1) {
        *reinterpret_cast<float4*>(
            &out[(size_t)TT * BB * MHW + (size_t)b * MHW + i]) = v;
    }
}

// ---------------------------------------------------------------------------
extern "C" void kernel_launch(void* const* d_in, const int* in_sizes, int n_in,
                              void* d_out, int out_size, void* d_ws, size_t ws_size,
                              hipStream_t stream) {
    const float* x = (const float*)d_in[0];
    const float* hprev = (const float*)d_in[1];
    const float* Wxh = (const float*)d_in[2];
    const float* Whh = (const float*)d_in[3];
    const float* bh = (const float*)d_in[4];
    float* out = (float*)d_out;

    float* xwb = out;                              // scratch in d_out
    unsigned short* hmod = (unsigned short*)d_ws;  // bf16, 16.7 MB

    k_xw<<<dim3(1020), 256, 0, stream>>>(x, Wxh, bh, xwb);

    for (int mi = 7; mi >= 0; --mi) {
        if (mi < 7)
            k_u<<<dim3(TT >> mi), 256, 0, stream>>>(Whh, hprev, hmod, xwb, mi);
        k_phase<<<8, 256, 0, stream>>>(Whh, hprev, xwb, hmod, mi);
    }

    k_out<<<dim3(128, 256), 256, 0, stream>>>(hmod, out);
}

// Round 19
// 379.920 us; speedup vs baseline: 1.1549x; 1.0115x over previous
//
#include <hip/hip_runtime.h>
#include <hip/hip_bf16.h>

// Clockwork RNN, hierarchical decomposition + bf16 MFMA GEMMs.
// Round 19: R18 base + k_xw v5 — counted-vmcnt chunk pipeline:
//   3 LDS buffers (72KB, 2 blocks/CU), per iter {vmcnt(6); s_barrier;
//   issue chunk c+2 into buffer freed by the barrier; compute chunk c}.
//   Never drains vmcnt to 0 in the loop (k_phase-producer pattern).
// k_u / k_phase (v6) / k_out unchanged from R13/R18.

#define TT 256
#define BB 128
#define INW 512
#define HH 128
#define MHW 1024

typedef __bf16 bf16x8 __attribute__((ext_vector_type(8)));
typedef __bf16 bf16x4 __attribute__((ext_vector_type(4)));
typedef float f32x4 __attribute__((ext_vector_type(4)));

__constant__ unsigned int c_hmod_off[8] = {
    0u, 4194304u, 6291456u, 7340032u, 7864320u, 8126464u, 8257536u, 8323072u};

__device__ __forceinline__ unsigned short f2bf(float f) {
    union { float f; unsigned int u; } v{f};
    unsigned int r = v.u + 0x7FFFu + ((v.u >> 16) & 1u);  // RNE
    return (unsigned short)(r >> 16);
}
__device__ __forceinline__ unsigned int pack2(float lo, float hi) {
    return (unsigned int)f2bf(lo) | ((unsigned int)f2bf(hi) << 16);
}
__device__ __forceinline__ float bf2f(unsigned short u) {
    union { unsigned int i; float f; } v;
    v.i = ((unsigned int)u) << 16;
    return v.f;
}

__device__ __forceinline__ void gld_lds16(const void* g, char* l) {
    __builtin_amdgcn_global_load_lds(
        (const __attribute__((address_space(1))) void*)g,
        (__attribute__((address_space(3))) void*)l, 16, 0, 0);
}

// Read one 16x32 bf16 fragment (8 bf16) from a swizzled bf16 tile ([rows][64] bf16).
__device__ __forceinline__ bf16x8 frag_ld(const char* tile, int row, int ks, int lane) {
    int off = (row * 128 + ks * 64 + (lane >> 4) * 16) ^ ((row & 7) << 4);
    return *reinterpret_cast<const bf16x8*>(tile + off);
}

// Read one fragment from a swizzled f32 tile with 256B rows ([rows][64] f32).
__device__ __forceinline__ bf16x8 frag_ld_f32(const char* tile, int row, int ks, int g) {
    int off = ((row << 8) + ks * 128 + g * 32) ^ ((row & 7) << 4);
    f32x4 a = *reinterpret_cast<const f32x4*>(tile + off);
    f32x4 b = *reinterpret_cast<const f32x4*>(tile + (off ^ 16));
    bf16x8 u;
    u[0] = (__bf16)a[0]; u[1] = (__bf16)a[1]; u[2] = (__bf16)a[2]; u[3] = (__bf16)a[3];
    u[4] = (__bf16)b[0]; u[5] = (__bf16)b[1]; u[6] = (__bf16)b[2]; u[7] = (__bf16)b[3];
    return u;
}

// Read one fragment from a swizzled f32 tile with 128B rows ([rows][32] f32).
__device__ __forceinline__ bf16x8 frag_ld_f32_k32(const char* tile, int row, int g) {
    int off = ((row << 7) + g * 32) ^ ((row & 7) << 4);
    f32x4 a = *reinterpret_cast<const f32x4*>(tile + off);
    f32x4 b = *reinterpret_cast<const f32x4*>(tile + (off ^ 16));
    bf16x8 u;
    u[0] = (__bf16)a[0]; u[1] = (__bf16)a[1]; u[2] = (__bf16)a[2]; u[3] = (__bf16)a[3];
    u[4] = (__bf16)b[0]; u[5] = (__bf16)b[1]; u[6] = (__bf16)b[2]; u[7] = (__bf16)b[3];
    return u;
}

// ---------------------------------------------------------------------------
// K_xw v5: 1020 blocks, 16 chunks of K=32, 3-buffer counted-vmcnt pipeline.
// Per wave per chunk: 6 gld_lds (4 W + 2 X). vmcnt(6) keeps chunk c+1 in
// flight while retiring chunk c.
// ---------------------------------------------------------------------------
#define XW_SYNC(NS)                                              \
    do {                                                         \
        asm volatile("s_waitcnt vmcnt(" NS ")" ::: "memory");    \
        __builtin_amdgcn_sched_barrier(0);                       \
        __builtin_amdgcn_s_barrier();                            \
        __builtin_amdgcn_sched_barrier(0);                       \
    } while (0)

__global__ __launch_bounds__(256) void k_xw(const float* __restrict__ x,
                                            const float* __restrict__ Wxh,
                                            const float* __restrict__ bh,
                                            float* __restrict__ xwb) {
    __shared__ char lds[3][24576];  // per buf: W [128][32]f32 (16KB) | X [64][32] (8KB)
    int id = blockIdx.x >> 1, half = blockIdx.x & 1;
    int rt = 0, rem = id;
    while (rem >= (256 >> rt)) { rem -= 256 >> rt; ++rt; }
    int t = rem << rt;

    int tid = threadIdx.x, lane = tid & 63, wid = tid >> 6;
    int l15 = lane & 15, g = lane >> 4;
    int wr = (wid >> 1) * 64, wc = (wid & 1) * 32;

    // Pre-swizzled per-lane sources (128B-row tiles).
    const float* gW[4];
    const float* gX[2];
    {
        int kb = (lane & 7) * 16;
#pragma unroll
        for (int p = 0; p < 4; ++p) {
            int row = p * 32 + wid * 8 + (lane >> 3);
            int kf = (kb ^ ((row & 7) << 4)) >> 2;
            gW[p] = Wxh + (size_t)(rt * 128 + row) * INW + kf;
        }
#pragma unroll
        for (int p = 0; p < 2; ++p) {
            int row = p * 32 + wid * 8 + (lane >> 3);
            int kf = (kb ^ ((row & 7) << 4)) >> 2;
            gX[p] = x + ((size_t)t * BB + half * 64 + row) * INW + kf;
        }
    }
    auto issue = [&](int c, int buf) {
        char* base = &lds[buf][0];
#pragma unroll
        for (int p = 0; p < 4; ++p)
            gld_lds16(gW[p] + c * 32, base + p * 4096 + wid * 1024);
#pragma unroll
        for (int p = 0; p < 2; ++p)
            gld_lds16(gX[p] + c * 32, base + 16384 + p * 4096 + wid * 1024);
    };

    f32x4 acc[4][2] = {};
    auto compute = [&](int buf) {
        bf16x8 fa[4], fb[2];
#pragma unroll
        for (int i = 0; i < 4; ++i)
            fa[i] = frag_ld_f32_k32(&lds[buf][0], wr + i * 16 + l15, g);
#pragma unroll
        for (int j = 0; j < 2; ++j)
            fb[j] = frag_ld_f32_k32(&lds[buf][16384], wc + j * 16 + l15, g);
#pragma unroll
        for (int i = 0; i < 4; ++i)
#pragma unroll
            for (int j = 0; j < 2; ++j)
                acc[i][j] = __builtin_amdgcn_mfma_f32_16x16x32_bf16(
                    fa[i], fb[j], acc[i][j], 0, 0, 0);
    };

    issue(0, 0);
    issue(1, 1);
    int cur = 0;
#pragma unroll 1
    for (int c = 0; c < 15; ++c) {
        XW_SYNC("6");  // retire chunk c; chunk c+1 stays in flight
        if (c < 14) {
            // buffer (c+2)%3 held chunk c-1; the barrier above guarantees all
            // waves finished computing it.
            int nb = cur + 2;
            if (nb >= 3) nb -= 3;
            issue(c + 2, nb);
        }
        compute(cur);
        cur = (cur == 2) ? 0 : cur + 1;
    }
    XW_SYNC("0");  // last chunk (15)
    compute(cur);

    // epilogue: bias + store
#pragma unroll
    for (int i = 0; i < 4; ++i) {
        int rbase = rt * 128 + wr + i * 16 + g * 4;
        float4 bias = *reinterpret_cast<const float4*>(&bh[rbase]);
#pragma unroll
        for (int j = 0; j < 2; ++j) {
            int b = half * 64 + wc + j * 16 + l15;
            float4 v = make_float4(acc[i][j][0] + bias.x, acc[i][j][1] + bias.y,
                                   acc[i][j][2] + bias.z, acc[i][j][3] + bias.w);
            *reinterpret_cast<float4*>(
                &xwb[(size_t)(t * BB + b) * MHW + rbase]) = v;
        }
    }
}

// ---------------------------------------------------------------------------
// K_u (unchanged R13): gld_lds staging for A (f32) and H (hprev f32 / hmod bf16).
// ---------------------------------------------------------------------------
__global__ __launch_bounds__(256) void k_u(const float* __restrict__ Whh,
                                           const float* __restrict__ hprev,
                                           const unsigned short* __restrict__ hmod,
                                           float* __restrict__ xwb, int mi) {
    __shared__ char lds[131072];
    char* ldsA0 = lds;
    char* ldsA1 = lds + 32768;
    char* ldsH0 = lds + 65536;
    char* ldsH1 = lds + 98304;
    int k = blockIdx.x;
    int t = k << mi;
    int tid = threadIdx.x, lane = tid & 63, wid = tid >> 6;
    int l15 = lane & 15, g = lane >> 4;
    int wr = (wid >> 1) * 64, wc = (wid & 1) * 64;
    int ntile = 2 * (7 - mi);

    const float* gA[8];
    {
        int kb = l15 * 16;
#pragma unroll
        for (int i = 0; i < 8; ++i) {
            int row = i * 16 + wid * 4 + g;
            int kf = (kb ^ ((row & 7) << 4)) >> 2;
            gA[i] = Whh + (size_t)(mi * HH + row) * MHW + kf;
        }
    }
    f32x4 acc[4][4] = {};

    if (k == 0) {
        const float* gH[8];
        {
            int kb = l15 * 16;
#pragma unroll
            for (int i = 0; i < 8; ++i) {
                int row = i * 16 + wid * 4 + g;
                int kf = (kb ^ ((row & 7) << 4)) >> 2;
                gH[i] = hprev + (size_t)row * MHW + kf;
            }
        }
        auto stage = [&](int tt, char* dA, char* dH) {
            int j = mi + 1 + (tt >> 1), c0 = (tt & 1) * 64;
            int off = j * HH + c0;
#pragma unroll
            for (int i = 0; i < 8; ++i)
                gld_lds16(gA[i] + off, dA + i * 4096 + wid * 1024);
#pragma unroll
            for (int i = 0; i < 8; ++i)
                gld_lds16(gH[i] + off, dH + i * 4096 + wid * 1024);
        };
        stage(0, ldsA0, ldsH0);
        for (int tt = 0; tt < ntile; ++tt) {
            int cur = tt & 1;
            __syncthreads();
            if (tt + 1 < ntile)
                stage(tt + 1, cur ? ldsA0 : ldsA1, cur ? ldsH0 : ldsH1);
            const char* sA = cur ? ldsA1 : ldsA0;
            const char* sH = cur ? ldsH1 : ldsH0;
#pragma unroll
            for (int ks = 0; ks < 2; ++ks) {
                bf16x8 fa[4], fb[4];
#pragma unroll
                for (int i = 0; i < 4; ++i) {
                    fa[i] = frag_ld_f32(sA, wr + i * 16 + l15, ks, g);
                    fb[i] = frag_ld_f32(sH, wc + i * 16 + l15, ks, g);
                }
#pragma unroll
                for (int i = 0; i < 4; ++i)
#pragma unroll
                    for (int jj = 0; jj < 4; ++jj)
                        acc[i][jj] = __builtin_amdgcn_mfma_f32_16x16x32_bf16(
                            fa[i], fb[jj], acc[i][jj], 0, 0, 0);
            }
        }
    } else {
        size_t hoff[4];
        {
            int cb = ((lane & 7) * 16) ^ ((lane >> 3) << 4);
#pragma unroll
            for (int p = 0; p < 4; ++p) {
                int row = p * 32 + wid * 8 + (lane >> 3);
                hoff[p] = (size_t)row * HH + (cb >> 1);
            }
        }
        auto stage = [&](int tt, char* dA, char* dH) {
            int j = mi + 1 + (tt >> 1), c0 = (tt & 1) * 64;
            int offA = j * HH + c0;
#pragma unroll
            for (int i = 0; i < 8; ++i)
                gld_lds16(gA[i] + offA, dA + i * 4096 + wid * 1024);
            const unsigned short* hb =
                hmod + c_hmod_off[j] + (size_t)((t - 1) >> j) * BB * HH + c0;
#pragma unroll
            for (int p = 0; p < 4; ++p)
                gld_lds16(hb + hoff[p], dH + p * 4096 + wid * 1024);
        };
        stage(0, ldsA0, ldsH0);
        for (int tt = 0; tt < ntile; ++tt) {
            int cur = tt & 1;
            __syncthreads();
            if (tt + 1 < ntile)
                stage(tt + 1, cur ? ldsA0 : ldsA1, cur ? ldsH0 : ldsH1);
            const char* sA = cur ? ldsA1 : ldsA0;
            const char* sH = cur ? ldsH1 : ldsH0;
#pragma unroll
            for (int ks = 0; ks < 2; ++ks) {
                bf16x8 fa[4], fb[4];
#pragma unroll
                for (int i = 0; i < 4; ++i) {
                    fa[i] = frag_ld_f32(sA, wr + i * 16 + l15, ks, g);
                    fb[i] = frag_ld(sH, wc + i * 16 + l15, ks, lane);
                }
#pragma unroll
                for (int i = 0; i < 4; ++i)
#pragma unroll
                    for (int jj = 0; jj < 4; ++jj)
                        acc[i][jj] = __builtin_amdgcn_mfma_f32_16x16x32_bf16(
                            fa[i], fb[jj], acc[i][jj], 0, 0, 0);
            }
        }
    }
#pragma unroll
    for (int i = 0; i < 4; ++i) {
        int rbase = wr + i * 16 + g * 4;
#pragma unroll
        for (int j = 0; j < 4; ++j) {
            int b = wc + j * 16 + l15;
            float4* p = reinterpret_cast<float4*>(
                &xwb[(size_t)(t * BB + b) * MHW + mi * HH + rbase]);
            float4 v = *p;
            v.x += acc[i][j][0]; v.y += acc[i][j][1];
            v.z += acc[i][j][2]; v.w += acc[i][j][3];
            *p = v;
        }
    }
}

// ---------------------------------------------------------------------------
// K_phase v6 (R13, verified): wave-specialized MFMA scan. 8 blocks x 16
// batches, 256 thr = waves {0,1}: compute, 2: u-producer, 3: h-storer.
// ---------------------------------------------------------------------------
#define SYNC_LDS()                                              \
    do {                                                        \
        asm volatile("s_waitcnt lgkmcnt(0)" ::: "memory");      \
        __builtin_amdgcn_sched_barrier(0);                      \
        __builtin_amdgcn_s_barrier();                           \
        __builtin_amdgcn_sched_barrier(0);                      \
    } while (0)
#define SYNC_VM24()                                             \
    do {                                                        \
        asm volatile("s_waitcnt vmcnt(24)" ::: "memory");       \
        __builtin_amdgcn_sched_barrier(0);                      \
        __builtin_amdgcn_s_barrier();                           \
        __builtin_amdgcn_sched_barrier(0);                      \
    } while (0)

__global__ __launch_bounds__(256) void k_phase(const float* __restrict__ Whh,
                                               const float* __restrict__ hprev,
                                               const float* __restrict__ xwb,
                                               unsigned short* __restrict__ hmod,
                                               int mi) {
    int b0 = blockIdx.x * 16;
    int tid = threadIdx.x, lane = tid & 63, wid = tid >> 6;
    int l15 = lane & 15, g = lane >> 4;
    __shared__ char sH[2][4096];   // [buf][b][r] bf16, swizzled
    __shared__ char sU[8][8192];   // u ring: [slot][r/4][b][4xf32], linear
    int Tm = TT >> mi;

    if (wid < 2) {
        // ================= compute waves =================
        bf16x8 Af[4][4];
        {
            const float* Ab = Whh + (size_t)(mi * HH) * MHW + mi * HH;
#pragma unroll
            for (int mm = 0; mm < 4; ++mm) {
                const float* row = Ab + (size_t)(64 * wid + mm * 16 + l15) * MHW;
#pragma unroll
                for (int kf = 0; kf < 4; ++kf) {
                    float4 v0 = *reinterpret_cast<const float4*>(row + kf * 32 + g * 8);
                    float4 v1 = *reinterpret_cast<const float4*>(row + kf * 32 + g * 8 + 4);
                    bf16x8 u;
                    u[0] = (__bf16)v0.x; u[1] = (__bf16)v0.y;
                    u[2] = (__bf16)v0.z; u[3] = (__bf16)v0.w;
                    u[4] = (__bf16)v1.x; u[5] = (__bf16)v1.y;
                    u[6] = (__bf16)v1.z; u[7] = (__bf16)v1.w;
                    Af[mm][kf] = u;
                }
            }
        }
        // initial H into buf 0 (tid 0..127 cover 16 batches x 128 rows)
#pragma unroll
        for (int p = 0; p < 2; ++p) {
            int tt = tid + p * 128;
            int b = tt >> 4, r8 = (tt & 15) * 8;
            const float* hp = hprev + (size_t)(b0 + b) * MHW + mi * HH + r8;
            float4 v0 = *reinterpret_cast<const float4*>(hp);
            float4 v1 = *reinterpret_cast<const float4*>(hp + 4);
            uint4 pk;
            pk.x = pack2(v0.x, v0.y); pk.y = pack2(v0.z, v0.w);
            pk.z = pack2(v1.x, v1.y); pk.w = pack2(v1.z, v1.w);
            int off = (b * 256 + r8 * 2) ^ ((b & 7) << 4);
            *reinterpret_cast<uint4*>(&sH[0][0] + off) = pk;
        }
        int roff[4], woff[4], uoff[4];
#pragma unroll
        for (int kf = 0; kf < 4; ++kf)
            roff[kf] = (l15 * 256 + kf * 64 + g * 16) ^ ((l15 & 7) << 4);
#pragma unroll
        for (int mm = 0; mm < 4; ++mm) {
            woff[mm] = (l15 * 256 + (64 * wid + mm * 16 + g * 4) * 2) ^ ((l15 & 7) << 4);
            uoff[mm] = (16 * wid + 4 * mm + g) * 256 + l15 * 16;
        }
        SYNC_LDS();

        for (int K = 0; K < Tm; ++K) {
            int cur = K & 1;
            const char* ub = &sU[K & 7][0];
            f32x4 acc[4], acc2[4];
#pragma unroll
            for (int mm = 0; mm < 4; ++mm) {
                acc[mm] = *reinterpret_cast<const f32x4*>(ub + uoff[mm]);
                acc2[mm] = (f32x4){0.f, 0.f, 0.f, 0.f};
            }
            bf16x8 Bf[4];
#pragma unroll
            for (int kf = 0; kf < 4; ++kf)
                Bf[kf] = *reinterpret_cast<const bf16x8*>(&sH[cur][0] + roff[kf]);
#pragma unroll
            for (int mm = 0; mm < 4; ++mm) {
                acc[mm] = __builtin_amdgcn_mfma_f32_16x16x32_bf16(
                    Af[mm][0], Bf[0], acc[mm], 0, 0, 0);
                acc2[mm] = __builtin_amdgcn_mfma_f32_16x16x32_bf16(
                    Af[mm][2], Bf[2], acc2[mm], 0, 0, 0);
                acc[mm] = __builtin_amdgcn_mfma_f32_16x16x32_bf16(
                    Af[mm][1], Bf[1], acc[mm], 0, 0, 0);
                acc2[mm] = __builtin_amdgcn_mfma_f32_16x16x32_bf16(
                    Af[mm][3], Bf[3], acc2[mm], 0, 0, 0);
            }
#pragma unroll
            for (int mm = 0; mm < 4; ++mm) {
                acc[mm] += acc2[mm];
                bf16x4 pk;
                pk[0] = (__bf16)acc[mm][0]; pk[1] = (__bf16)acc[mm][1];
                pk[2] = (__bf16)acc[mm][2]; pk[3] = (__bf16)acc[mm][3];
                *reinterpret_cast<bf16x4*>(&sH[cur ^ 1][0] + woff[mm]) = pk;
            }
            SYNC_LDS();
        }
    } else if (wid == 2) {
        // ================= u producer =================
        const float* ubase = xwb + (size_t)(b0 + l15) * MHW + mi * HH + g * 4;
#pragma unroll
        for (int q = 0; q < 4; ++q) {  // prologue: slots 0..3
            int t = min(q, Tm - 1) << mi;
            const float* pt = ubase + (size_t)t * BB * MHW;
#pragma unroll
            for (int p = 0; p < 8; ++p)
                gld_lds16(pt + p * 16, &sU[q][0] + p * 1024);
        }
        SYNC_VM24();  // retires slot 0
        for (int K = 0; K < Tm; ++K) {
            int t = min(K + 4, Tm - 1) << mi;
            int slot = (K + 4) & 7;
            const float* pt = ubase + (size_t)t * BB * MHW;
#pragma unroll
            for (int p = 0; p < 8; ++p)
                gld_lds16(pt + p * 16, &sU[slot][0] + p * 1024);
            SYNC_VM24();  // retires slot K+1 (needed next step)
        }
        asm volatile("s_waitcnt vmcnt(0)" ::: "memory");
    } else {
        // ================= h storer =================
        int bq = lane >> 2;
        int rr = (lane & 3) * 32;
        unsigned short* hm =
            hmod + c_hmod_off[mi] + (size_t)(b0 + bq) * HH + rr;
        int soff[4];
#pragma unroll
        for (int c = 0; c < 4; ++c)
            soff[c] = (bq * 256 + (rr + c * 8) * 2) ^ ((bq & 7) << 4);
        SYNC_LDS();
        for (int K = 0; K < Tm; ++K) {
            if (K >= 1) {
                uint4 h[4];
#pragma unroll
                for (int c = 0; c < 4; ++c)
                    h[c] = *reinterpret_cast<const uint4*>(&sH[K & 1][0] + soff[c]);
                unsigned short* dst = hm + (size_t)(K - 1) * BB * HH;
#pragma unroll
                for (int c = 0; c < 4; ++c)
                    *reinterpret_cast<uint4*>(dst + c * 8) = h[c];
            }
            SYNC_LDS();
        }
        {  // final state s_Tm -> hmod[Tm-1]
            uint4 h[4];
#pragma unroll
            for (int c = 0; c < 4; ++c)
                h[c] = *reinterpret_cast<const uint4*>(&sH[Tm & 1][0] + soff[c]);
            unsigned short* dst = hm + (size_t)(Tm - 1) * BB * HH;
#pragma unroll
            for (int c = 0; c < 4; ++c)
                *reinterpret_cast<uint4*>(dst + c * 8) = h[c];
        }
    }
}

// ---------------------------------------------------------------------------
// K_out (unchanged): out[t][b][j*H + h] = bf2f(Hmod[j][t>>j][b][h]); h_last.
// ---------------------------------------------------------------------------
__global__ __launch_bounds__(256) void k_out(const unsigned short* __restrict__ hmod,
                                             float* __restrict__ out) {
    int b = blockIdx.x, t = blockIdx.y;
    int tid = threadIdx.x;
    int i = tid * 4;
    int j = i >> 7;
    int k = t >> j;
    ushort4 h = *reinterpret_cast<const ushort4*>(
        &hmod[c_hmod_off[j] + ((size_t)k * BB + b) * HH + (i & 127)]);
    float4 v = make_float4(bf2f(h.x), bf2f(h.y), bf2f(h.z), bf2f(h.w));
    *reinterpret_cast<float4*>(&out[((size_t)t * BB + b) * MHW + i]) = v;
    if (t == TT - 1) {
        *reinterpret_cast<float4*>(
            &out[(size_t)TT * BB * MHW + (size_t)b * MHW + i]) = v;
    }
}

// ---------------------------------------------------------------------------
extern "C" void kernel_launch(void* const* d_in, const int* in_sizes, int n_in,
                              void* d_out, int out_size, void* d_ws, size_t ws_size,
                              hipStream_t stream) {
    const float* x = (const float*)d_in[0];
    const float* hprev = (const float*)d_in[1];
    const float* Wxh = (const float*)d_in[2];
    const float* Whh = (const float*)d_in[3];
    const float* bh = (const float*)d_in[4];
    float* out = (float*)d_out;

    float* xwb = out;                              // scratch in d_out
    unsigned short* hmod = (unsigned short*)d_ws;  // bf16, 16.7 MB

    k_xw<<<dim3(1020), 256, 0, stream>>>(x, Wxh, bh, xwb);

    for (int mi = 7; mi >= 0; --mi) {
        if (mi < 7)
            k_u<<<dim3(TT >> mi), 256, 0, stream>>>(Whh, hprev, hmod, xwb, mi);
        k_phase<<<8, 256, 0, stream>>>(Whh, hprev, xwb, hmod, mi);
    }

    k_out<<<dim3(128, 256), 256, 0, stream>>>(hmod, out);
}